// Round 5
// baseline (838.376 us; speedup 1.0000x reference)
//
#include <hip/hip_runtime.h>
#include <math.h>

typedef unsigned short u16;
typedef unsigned int u32;
typedef short short8 __attribute__((ext_vector_type(8)));
typedef float f32x4 __attribute__((ext_vector_type(4)));

#define SCALE_QK 0.17677669529663687f  // 32^-0.5

__device__ __forceinline__ float b2f(u16 v) { return __uint_as_float(((u32)v) << 16); }
__device__ __forceinline__ u16 f2b(float f) {
  u32 u = __float_as_uint(f);
  return (u16)((u + 0x7fffu + ((u >> 16) & 1u)) >> 16);
}

// ---- K0: fold BN params, premix bias through th1, convert weights to bf16 ----
__global__ __launch_bounds__(256) void k_pre(
    const float* __restrict__ th1w, const float* __restrict__ th1b, const float* __restrict__ ab,
    const float* __restrict__ qb, const float* __restrict__ qs, const float* __restrict__ qo,
    const float* __restrict__ kb, const float* __restrict__ ks, const float* __restrict__ ko,
    const float* __restrict__ vb, const float* __restrict__ vs, const float* __restrict__ vo,
    const float* __restrict__ pb, const float* __restrict__ ps, const float* __restrict__ po,
    const float* __restrict__ qw, const float* __restrict__ kw,
    const float* __restrict__ vw, const float* __restrict__ pw,
    float* __restrict__ bias2, float* __restrict__ alpha, float* __restrict__ beta,
    float* __restrict__ alphap, float* __restrict__ betap,
    u16* __restrict__ Wq, u16* __restrict__ Wk, u16* __restrict__ Wv, u16* __restrict__ Wp)
{
  int gid = blockIdx.x * 256 + threadIdx.x;
  if (gid < 19208) {
    int i = gid / 2401, rem = gid % 2401, n = rem / 49, m = rem % 49;
    int ry = abs(n / 7 - m / 7), rx = abs(n % 7 - m % 7);
    int idx = ry * 7 + rx;
    float acc = th1b[i];
    #pragma unroll
    for (int j = 0; j < 8; j++) acc += th1w[i * 8 + j] * ab[j * 49 + idx];
    bias2[gid] = acc;
  } else if (gid < 20744) {
    int c = gid - 19208;
    const float *s, *bb, *oo; int idx;
    if (c < 256)      { s = qs; bb = qb; oo = qo; idx = c; }
    else if (c < 512) { s = ks; bb = kb; oo = ko; idx = c - 256; }
    else              { s = vs; bb = vb; oo = vo; idx = c - 512; }
    float sv = s[idx];
    alpha[c] = sv;
    beta[c] = sv * bb[idx] + oo[idx];
  } else if (gid < 21128) {
    int c = gid - 20744;
    float sv = ps[c];
    alphap[c] = sv;
    betap[c] = sv * pb[c] + po[c];
  } else {
    int g = gid - 21128;
    if (g < 98304)       Wq[g] = f2b(qw[g]);
    else if (g < 196608) Wk[g - 98304] = f2b(kw[g - 98304]);
    else if (g < 589824) Wv[g - 196608] = f2b(vw[g - 196608]);
    else if (g < 983040) Wp[g - 589824] = f2b(pw[g - 589824]);
  }
}

// ---- K1: fused qkv-projection + talking-heads attention + dwconv + GELU ----
// One block per batch. Writes only Z[b][1024][49] (bf16).
__global__ __launch_bounds__(512, 1) void k_fused(
    const float* __restrict__ x,
    const u16* __restrict__ Wq, const u16* __restrict__ Wk, const u16* __restrict__ Wv,
    const float* __restrict__ alpha, const float* __restrict__ beta,
    const float* __restrict__ bias2,
    const float* __restrict__ th1w, const float* __restrict__ th1b,
    const float* __restrict__ th2w, const float* __restrict__ th2b,
    const float* __restrict__ vlw, const float* __restrict__ vlb,
    const float* __restrict__ vls, const float* __restrict__ vlo,
    u16* __restrict__ Z)
{
  __shared__ u16 lds[63008];          // 126016 B
  u16* XT = lds;                      // [64][392] x^T bf16, rows n>=49 zero
  u16* QT = lds + 25088;              // [64][40]  q^T (per head)
  u16* KT = lds + 27648;              // [64][40]  k^T (per head)
  u16* SB = lds + 30208;              // [8][52][56] scores, zero padded
  u16* VT = lds + 53504;              // [128][72] v tile (per head), cols>=49 zero
  float* THf = (float*)(lds + 62720); // th1w(64) th1b(8) th2w(64) th2b(8)

  int t = threadIdx.x, wv = t >> 6, l = t & 63, quad = l >> 4, l16 = l & 15;
  int b = blockIdx.x;
  const float* xb = x + (size_t)b * 18816;

  { // zero SB + VT (contiguous)
    u32* zp = (u32*)(lds + 30208);
    for (int e = t; e < 16256; e += 512) zp[e] = 0;
  }
  if (t < 64)       THf[t] = th1w[t];
  else if (t < 72)  THf[t] = th1b[t - 64];
  else if (t < 136) THf[t] = th2w[t - 72];
  else if (t < 144) THf[t] = th2b[t - 136];
  // stage x^T (coalesced reads), rows n>=49 zeroed
  for (int e = t; e < 18816; e += 512) {
    int k = e / 49, n = e - k * 49;
    XT[n * 392 + k] = f2b(xb[e]);
  }
  for (int e = t; e < 2880; e += 512) {
    int r = e / 192, kk = e - r * 192;
    ((u32*)(XT + (49 + r) * 392))[kk] = 0;
  }
  __syncthreads();

  // ---- per head: q/k GEMM -> QT/KT, then QK^T -> SB ----
  const u16* Wqk = (wv < 4) ? Wq : Wk;
  u16* QKdst = (wv < 4) ? QT : KT;
  int abase = (wv < 4) ? 0 : 256;
  int mRow = (wv >> 1) & 1;
  int ntb = (wv & 1) * 2;

  for (int h = 0; h < 8; h++) {
    f32x4 acc0 = {}, acc1 = {};
    int arow = h * 32 + mRow * 16 + l16;
    for (int k0 = 0; k0 < 384; k0 += 32) {
      short8 af = *(const short8*)(Wqk + (size_t)arow * 384 + k0 + quad * 8);
      short8 b0 = *(const short8*)(&XT[(ntb * 16 + l16) * 392 + k0 + quad * 8]);
      short8 b1 = *(const short8*)(&XT[((ntb + 1) * 16 + l16) * 392 + k0 + quad * 8]);
      acc0 = __builtin_amdgcn_mfma_f32_16x16x32_bf16(af, b0, acc0, 0, 0, 0);
      acc1 = __builtin_amdgcn_mfma_f32_16x16x32_bf16(af, b1, acc1, 0, 0, 0);
    }
    #pragma unroll
    for (int reg = 0; reg < 4; reg++) {
      int cl = mRow * 16 + quad * 4 + reg;
      float al = alpha[abase + h * 32 + cl], be = beta[abase + h * 32 + cl];
      int n0 = ntb * 16 + l16;
      QKdst[n0 * 40 + cl] = f2b(acc0[reg] * al + be);
      QKdst[(n0 + 16) * 40 + cl] = f2b(acc1[reg] * al + be);
    }
    __syncthreads();
    #pragma unroll
    for (int ui = 0; ui < 2; ui++) {
      int u = wv * 2 + ui, tn = u >> 2, tm = u & 3;
      short8 a = *(const short8*)(&QT[(tn * 16 + l16) * 40 + quad * 8]);
      short8 bb = *(const short8*)(&KT[(tm * 16 + l16) * 40 + quad * 8]);
      f32x4 c = {};
      c = __builtin_amdgcn_mfma_f32_16x16x32_bf16(a, bb, c, 0, 0, 0);
      #pragma unroll
      for (int r = 0; r < 4; r++) {
        int n = tn * 16 + quad * 4 + r, m = tm * 16 + l16;
        if (n < 49 && m < 49) SB[(h * 52 + n) * 56 + m] = f2b(c[r] * SCALE_QK);
      }
    }
    __syncthreads();
  }

  // ---- mix1 + premixed bias ----
  for (int e = t; e < 2401; e += 512) {
    int n = e / 49, m = e - n * 49;
    float s[8], uo[8];
    #pragma unroll
    for (int j = 0; j < 8; j++) s[j] = b2f(SB[(j * 52 + n) * 56 + m]);
    #pragma unroll
    for (int i = 0; i < 8; i++) {
      float a2 = bias2[(i * 49 + n) * 49 + m];
      #pragma unroll
      for (int j = 0; j < 8; j++) a2 += THf[i * 8 + j] * s[j];
      uo[i] = a2;
    }
    #pragma unroll
    for (int i = 0; i < 8; i++) SB[(i * 52 + n) * 56 + m] = f2b(uo[i]);
  }
  __syncthreads();
  // ---- softmax over m ----
  if (t < 392) {
    int i = t / 49, n = t - i * 49;
    u16* row = &SB[(i * 52 + n) * 56];
    float v[49]; float mx = -1e30f;
    #pragma unroll
    for (int m = 0; m < 49; m++) { v[m] = b2f(row[m]); mx = fmaxf(mx, v[m]); }
    float sum = 0.f;
    #pragma unroll
    for (int m = 0; m < 49; m++) { v[m] = __expf(v[m] - mx); sum += v[m]; }
    float inv = 1.f / sum;
    #pragma unroll
    for (int m = 0; m < 49; m++) row[m] = f2b(v[m] * inv);
  }
  __syncthreads();
  // ---- mix2 ----
  for (int e = t; e < 2401; e += 512) {
    int n = e / 49, m = e - n * 49;
    float s[8], uo[8];
    #pragma unroll
    for (int j = 0; j < 8; j++) s[j] = b2f(SB[(j * 52 + n) * 56 + m]);
    #pragma unroll
    for (int i = 0; i < 8; i++) {
      float a2 = THf[136 + i];
      #pragma unroll
      for (int j = 0; j < 8; j++) a2 += THf[72 + i * 8 + j] * s[j];
      uo[i] = a2;
    }
    #pragma unroll
    for (int i = 0; i < 8; i++) SB[(i * 52 + n) * 56 + m] = f2b(uo[i]);
  }
  __syncthreads();

  // ---- per head: v GEMM -> VT, P@V, dwconv+GELU -> Z ----
  u16* Zb = Z + (size_t)b * 50176;
  for (int h = 0; h < 8; h++) {
    f32x4 va[4] = {};
    int vrowi = h * 128 + wv * 16 + l16;
    for (int k0 = 0; k0 < 384; k0 += 32) {
      short8 af = *(const short8*)(Wv + (size_t)vrowi * 384 + k0 + quad * 8);
      #pragma unroll
      for (int nt = 0; nt < 4; nt++) {
        short8 bf = *(const short8*)(&XT[(nt * 16 + l16) * 392 + k0 + quad * 8]);
        va[nt] = __builtin_amdgcn_mfma_f32_16x16x32_bf16(af, bf, va[nt], 0, 0, 0);
      }
    }
    #pragma unroll
    for (int reg = 0; reg < 4; reg++) {
      int dl = wv * 16 + quad * 4 + reg;
      int c = h * 128 + dl;
      float al = alpha[512 + c], be = beta[512 + c];
      #pragma unroll
      for (int nt = 0; nt < 4; nt++) {
        int m = nt * 16 + l16;
        if (m < 49) VT[dl * 72 + m] = f2b(va[nt][reg] * al + be);
      }
    }
    __syncthreads();
    f32x4 oa[4] = {};
    #pragma unroll
    for (int ks2 = 0; ks2 < 2; ks2++) {
      int mb = ks2 * 32 + quad * 8;
      short8 bf = *(const short8*)(&VT[(wv * 16 + l16) * 72 + mb]);
      #pragma unroll
      for (int tn = 0; tn < 4; tn++) {
        short8 af = *(const short8*)(&SB[(h * 52 + tn * 16 + l16) * 56 + mb]);
        oa[tn] = __builtin_amdgcn_mfma_f32_16x16x32_bf16(af, bf, oa[tn], 0, 0, 0);
      }
    }
    int d = wv * 16 + l16, c = h * 128 + d;
    float w9[9];
    #pragma unroll
    for (int j = 0; j < 9; j++) w9[j] = vlw[c * 9 + j];
    float sv = vls[c];
    float cb = sv * vlb[c] + vlo[c];
    const u16* vtr = &VT[d * 72];
    #pragma unroll
    for (int tn = 0; tn < 4; tn++) {
      #pragma unroll
      for (int r = 0; r < 4; r++) {
        int n = tn * 16 + quad * 4 + r;
        if (n < 49) {
          int yi = n / 7, xi = n - yi * 7;
          float conv = 0.f;
          #pragma unroll
          for (int ky = 0; ky < 3; ky++) {
            int y2 = yi + ky - 1;
            if (y2 < 0 || y2 > 6) continue;
            #pragma unroll
            for (int kx = 0; kx < 3; kx++) {
              int x2 = xi + kx - 1;
              if (x2 < 0 || x2 > 6) continue;
              conv += b2f(vtr[y2 * 7 + x2]) * w9[ky * 3 + kx];
            }
          }
          float z = oa[tn][r] + conv * sv + cb;
          float g = z * 0.5f * (1.0f + erff(z * 0.70710678118654752f));
          Zb[(size_t)c * 49 + n] = f2b(g);
        }
      }
    }
    __syncthreads();
  }
}

// ---- K2: output projection GEMM (bf16 weights) -> d_out (f32) ----
__global__ __launch_bounds__(256) void k_proj(
    const u16* __restrict__ Wp, const u16* __restrict__ Z,
    const float* __restrict__ alphap, const float* __restrict__ betap,
    float* __restrict__ out)
{
  __shared__ u16 As[384 * 40];
  __shared__ u16 Zs[64 * 40];
  int b = blockIdx.x;
  int t = threadIdx.x, wv = t >> 6, l = t & 63, quad = l >> 4, l16 = l & 15;
  const u16* Zb = Z + (size_t)b * 50176;
  f32x4 acc[6][4] = {};
  for (int k0 = 0; k0 < 1024; k0 += 32) {
    for (int ch = t; ch < 1536; ch += 256) {
      int r = ch >> 2, kk8 = (ch & 3) * 8;
      *(uint4*)(&As[r * 40 + kk8]) = *(const uint4*)(Wp + (size_t)r * 1024 + k0 + kk8);
    }
    for (int e = t; e < 2048; e += 256) {
      int n = e >> 5, kk = e & 31;
      Zs[n * 40 + kk] = (n < 49) ? Zb[(size_t)(k0 + kk) * 49 + n] : (u16)0;
    }
    __syncthreads();
    short8 af[6];
    #pragma unroll
    for (int rt = 0; rt < 6; rt++)
      af[rt] = *(const short8*)(&As[(wv * 96 + rt * 16 + l16) * 40 + quad * 8]);
    #pragma unroll
    for (int ct = 0; ct < 4; ct++) {
      short8 bfr = *(const short8*)(&Zs[(ct * 16 + l16) * 40 + quad * 8]);
      #pragma unroll
      for (int rt = 0; rt < 6; rt++)
        acc[rt][ct] = __builtin_amdgcn_mfma_f32_16x16x32_bf16(af[rt], bfr, acc[rt][ct], 0, 0, 0);
    }
    __syncthreads();
  }
  float* ob = out + (size_t)b * 18816;
  #pragma unroll
  for (int rt = 0; rt < 6; rt++) {
    #pragma unroll
    for (int reg = 0; reg < 4; reg++) {
      int c = wv * 96 + rt * 16 + quad * 4 + reg;
      float al = alphap[c], be = betap[c];
      #pragma unroll
      for (int ct = 0; ct < 4; ct++) {
        int n = ct * 16 + l16;
        if (n < 49) ob[(size_t)c * 49 + n] = acc[rt][ct][reg] * al + be;
      }
    }
  }
}

extern "C" void kernel_launch(void* const* d_in, const int* in_sizes, int n_in,
                              void* d_out, int out_size, void* d_ws, size_t ws_size,
                              hipStream_t stream) {
  const float* x    = (const float*)d_in[0];
  const float* qw   = (const float*)d_in[1];
  const float* qb   = (const float*)d_in[2];
  const float* qs   = (const float*)d_in[3];
  const float* qo   = (const float*)d_in[4];
  const float* kw   = (const float*)d_in[5];
  const float* kb   = (const float*)d_in[6];
  const float* ks   = (const float*)d_in[7];
  const float* ko   = (const float*)d_in[8];
  const float* vw   = (const float*)d_in[9];
  const float* vb   = (const float*)d_in[10];
  const float* vs   = (const float*)d_in[11];
  const float* vo   = (const float*)d_in[12];
  const float* vlw  = (const float*)d_in[13];
  const float* vlb  = (const float*)d_in[14];
  const float* vls  = (const float*)d_in[15];
  const float* vlo  = (const float*)d_in[16];
  const float* th1w = (const float*)d_in[17];
  const float* th1b = (const float*)d_in[18];
  const float* th2w = (const float*)d_in[19];
  const float* th2b = (const float*)d_in[20];
  const float* pw   = (const float*)d_in[21];
  const float* pb   = (const float*)d_in[22];
  const float* ps   = (const float*)d_in[23];
  const float* po   = (const float*)d_in[24];
  const float* ab   = (const float*)d_in[25];
  float* out = (float*)d_out;
  char* ws = (char*)d_ws;

  // ws layout (bytes) — total ~104.8 MB (was 257 MB: overflow corrupted
  // neighboring allocations after run 1 — see round-4 post-mortem)
  float* bias2  = (float*)(ws + 0);          // 19208 f
  float* alpha  = (float*)(ws + 77056);      // 1536 f
  float* beta   = (float*)(ws + 83200);      // 1536 f
  float* alphap = (float*)(ws + 89344);      // 384 f
  float* betap  = (float*)(ws + 90880);      // 384 f
  u16*   Wq16   = (u16*)(ws + 92416);        // 256*384
  u16*   Wk16   = (u16*)(ws + 289024);       // 256*384
  u16*   Wv16   = (u16*)(ws + 485632);       // 1024*384
  u16*   Wp16   = (u16*)(ws + 1272064);      // 384*1024
  u16*   Z      = (u16*)(ws + 2058496);      // 1024*1024*49 bf16 = 102.8 MB

  k_pre<<<3923, 256, 0, stream>>>(th1w, th1b, ab, qb, qs, qo, kb, ks, ko,
                                  vb, vs, vo, pb, ps, po, qw, kw, vw, pw,
                                  bias2, alpha, beta, alphap, betap,
                                  Wq16, Wk16, Wv16, Wp16);
  k_fused<<<1024, 512, 0, stream>>>(x, Wq16, Wk16, Wv16, alpha, beta, bias2,
                                    th1w, th1b, th2w, th2b,
                                    vlw, vlb, vls, vlo, Z);
  k_proj<<<1024, 256, 0, stream>>>(Wp16, Z, alphap, betap, out);
}

// Round 6
// 704.197 us; speedup vs baseline: 1.1905x; 1.1905x over previous
//
#include <hip/hip_runtime.h>
#include <math.h>

typedef unsigned short u16;
typedef unsigned int u32;
typedef short short8 __attribute__((ext_vector_type(8)));
typedef float f32x4 __attribute__((ext_vector_type(4)));

#define SCALE_QK 0.17677669529663687f  // 32^-0.5
#define POFF 26880                     // P offset (u16) inside each Z[b] slab of 50176

__device__ __forceinline__ float b2f(u16 v) { return __uint_as_float(((u32)v) << 16); }
__device__ __forceinline__ u16 f2b(float f) {
  u32 u = __float_as_uint(f);
  return (u16)((u + 0x7fffu + ((u >> 16) & 1u)) >> 16);
}

// ---- K0: fold BN params, premix bias through th1, convert weights to bf16 ----
__global__ __launch_bounds__(256) void k_pre(
    const float* __restrict__ th1w, const float* __restrict__ th1b, const float* __restrict__ ab,
    const float* __restrict__ qb, const float* __restrict__ qs, const float* __restrict__ qo,
    const float* __restrict__ kb, const float* __restrict__ ks, const float* __restrict__ ko,
    const float* __restrict__ vb, const float* __restrict__ vs, const float* __restrict__ vo,
    const float* __restrict__ pb, const float* __restrict__ ps, const float* __restrict__ po,
    const float* __restrict__ qw, const float* __restrict__ kw,
    const float* __restrict__ vw, const float* __restrict__ pw,
    float* __restrict__ bias2, float* __restrict__ alpha, float* __restrict__ beta,
    float* __restrict__ alphap, float* __restrict__ betap,
    u16* __restrict__ Wqk, u16* __restrict__ Wv, u16* __restrict__ Wp)
{
  int gid = blockIdx.x * 256 + threadIdx.x;
  if (gid < 19208) {
    int i = gid / 2401, rem = gid % 2401, n = rem / 49, m = rem % 49;
    int ry = abs(n / 7 - m / 7), rx = abs(n % 7 - m % 7);
    int idx = ry * 7 + rx;
    float acc = th1b[i];
    #pragma unroll
    for (int j = 0; j < 8; j++) acc += th1w[i * 8 + j] * ab[j * 49 + idx];
    bias2[gid] = acc;
  } else if (gid < 20744) {
    int c = gid - 19208;
    const float *s, *bb, *oo; int idx;
    if (c < 256)      { s = qs; bb = qb; oo = qo; idx = c; }
    else if (c < 512) { s = ks; bb = kb; oo = ko; idx = c - 256; }
    else              { s = vs; bb = vb; oo = vo; idx = c - 512; }
    float sv = s[idx];
    alpha[c] = sv;
    beta[c] = sv * bb[idx] + oo[idx];
  } else if (gid < 21128) {
    int c = gid - 20744;
    float sv = ps[c];
    alphap[c] = sv;
    betap[c] = sv * pb[c] + po[c];
  } else {
    int g = gid - 21128;
    if (g < 98304)       Wqk[g] = f2b(qw[g]);                 // q rows 0..255
    else if (g < 196608) Wqk[g] = f2b(kw[g - 98304]);         // k rows 256..511
    else if (g < 589824) Wv[g - 196608] = f2b(vw[g - 196608]);
    else if (g < 983040) Wp[g - 589824] = f2b(pw[g - 589824]);
  }
}

// ---- K1: per batch q/k GEMM + QK^T -> raw scaled scores into P (in Z tail) ----
__global__ __launch_bounds__(512, 4) void k_qk(
    const float* __restrict__ x, const u16* __restrict__ Wqk,
    const float* __restrict__ alpha, const float* __restrict__ beta,
    u16* __restrict__ Zs)
{
  __shared__ u16 lds[37376];   // 74752 B -> 2 blocks/CU
  u16* XT = lds;               // [64][408]  (stride 816B: 16B-aligned, ~2-way banks)
  u16* Tq = lds + 26112;       // [64][88]
  u16* Tk = lds + 31744;       // [64][88]
  int t = threadIdx.x, wv = t >> 6, l = t & 63, quad = l >> 4, l16 = l & 15;
  int b = blockIdx.x;
  const float* xb = x + (size_t)b * 18816;

  for (int e = t; e < 18816; e += 512) {
    int k = e / 49, n = e - k * 49;
    XT[n * 408 + k] = f2b(xb[e]);
  }
  for (int e = t; e < 3060; e += 512) {  // zero rows 49..63 (must be finite!)
    int r = e / 204, kk = e - r * 204;
    ((u32*)(XT + (49 + r) * 408))[kk] = 0;
  }
  __syncthreads();

  u16* Pg = Zs + (size_t)b * 50176 + POFF;   // [8][52][56]
  int isK = wv >= 4, wl = wv & 3;
  for (int hp = 0; hp < 4; hp++) {
    int cbase = (isK ? 256 : 0) + hp * 64 + wl * 16;
    f32x4 acc[4] = {};
    const u16* Wr = Wqk + (size_t)(cbase + l16) * 384;
    #pragma unroll
    for (int ks = 0; ks < 12; ks++) {
      short8 af = *(const short8*)(Wr + ks * 32 + quad * 8);
      #pragma unroll
      for (int nt = 0; nt < 4; nt++) {
        short8 bf = *(const short8*)(&XT[(nt * 16 + l16) * 408 + ks * 32 + quad * 8]);
        acc[nt] = __builtin_amdgcn_mfma_f32_16x16x32_bf16(af, bf, acc[nt], 0, 0, 0);
      }
    }
    u16* Tdst = isK ? Tk : Tq;
    #pragma unroll
    for (int reg = 0; reg < 4; reg++) {
      int c = cbase + quad * 4 + reg;
      float al = alpha[c], be = beta[c];
      int cl = wl * 16 + quad * 4 + reg;
      #pragma unroll
      for (int nt = 0; nt < 4; nt++)
        Tdst[(nt * 16 + l16) * 88 + cl] = f2b(acc[nt][reg] * al + be);
    }
    __syncthreads();
    #pragma unroll
    for (int ui = 0; ui < 4; ui++) {
      int u = wv * 4 + ui;                    // 32 tiles: 2 heads x 4x4
      int hl = u >> 4, tn = (u >> 2) & 3, tm = u & 3;
      short8 a  = *(const short8*)(&Tq[(tn * 16 + l16) * 88 + hl * 32 + quad * 8]);
      short8 bb = *(const short8*)(&Tk[(tm * 16 + l16) * 88 + hl * 32 + quad * 8]);
      f32x4 c = {};
      c = __builtin_amdgcn_mfma_f32_16x16x32_bf16(a, bb, c, 0, 0, 0);
      int h = hp * 2 + hl;
      #pragma unroll
      for (int r = 0; r < 4; r++) {
        int n = tn * 16 + quad * 4 + r, m = tm * 16 + l16;
        if (n < 49 && m < 49) Pg[(h * 52 + n) * 56 + m] = f2b(c[r] * SCALE_QK);
      }
    }
    __syncthreads();
  }
}

// ---- K2: mix1 + bias, softmax, mix2 — in place on P ----
__global__ __launch_bounds__(256, 4) void k_mix(
    u16* __restrict__ Zs, const float* __restrict__ bias2,
    const float* __restrict__ th1w, const float* __restrict__ th1b,
    const float* __restrict__ th2w, const float* __restrict__ th2b)
{
  __shared__ u16 SB[23296];    // [8][52][56]
  __shared__ float TH[144];
  int t = threadIdx.x, b = blockIdx.x;
  u32* Pg32 = (u32*)(Zs + (size_t)b * 50176 + POFF);
  for (int e = t; e < 11648; e += 256) ((u32*)SB)[e] = Pg32[e];
  if (t < 64)       TH[t] = th1w[t];
  else if (t < 72)  TH[t] = th1b[t - 64];
  else if (t < 136) TH[t] = th2w[t - 72];
  else if (t < 144) TH[t] = th2b[t - 136];
  __syncthreads();
  for (int e = t; e < 2401; e += 256) {
    int n = e / 49, m = e - n * 49;
    float s[8], uo[8];
    #pragma unroll
    for (int j = 0; j < 8; j++) s[j] = b2f(SB[(j * 52 + n) * 56 + m]);
    #pragma unroll
    for (int i = 0; i < 8; i++) {
      float a2 = bias2[(i * 49 + n) * 49 + m];
      #pragma unroll
      for (int j = 0; j < 8; j++) a2 += TH[i * 8 + j] * s[j];
      uo[i] = a2;
    }
    #pragma unroll
    for (int i = 0; i < 8; i++) SB[(i * 52 + n) * 56 + m] = f2b(uo[i]);
  }
  __syncthreads();
  for (int r0 = t; r0 < 392; r0 += 256) {
    int i = r0 / 49, n = r0 - i * 49;
    u16* row = &SB[(i * 52 + n) * 56];
    float v[49]; float mx = -1e30f;
    #pragma unroll
    for (int m = 0; m < 49; m++) { v[m] = b2f(row[m]); mx = fmaxf(mx, v[m]); }
    float sum = 0.f;
    #pragma unroll
    for (int m = 0; m < 49; m++) { v[m] = __expf(v[m] - mx); sum += v[m]; }
    float inv = 1.f / sum;
    #pragma unroll
    for (int m = 0; m < 49; m++) row[m] = f2b(v[m] * inv);
  }
  __syncthreads();
  for (int e = t; e < 2401; e += 256) {
    int n = e / 49, m = e - n * 49;
    float s[8], uo[8];
    #pragma unroll
    for (int j = 0; j < 8; j++) s[j] = b2f(SB[(j * 52 + n) * 56 + m]);
    #pragma unroll
    for (int i = 0; i < 8; i++) {
      float a2 = TH[136 + i];
      #pragma unroll
      for (int j = 0; j < 8; j++) a2 += TH[72 + i * 8 + j] * s[j];
      uo[i] = a2;
    }
    #pragma unroll
    for (int i = 0; i < 8; i++) SB[(i * 52 + n) * 56 + m] = f2b(uo[i]);
  }
  __syncthreads();
  for (int e = t; e < 11648; e += 256) Pg32[e] = ((u32*)SB)[e];
}

// ---- K3: per batch v GEMM + P@V + dwconv + GELU -> Z (overwrites P region last) ----
__global__ __launch_bounds__(512, 4) void k_av(
    const float* __restrict__ x, const u16* __restrict__ Wv,
    const float* __restrict__ alpha, const float* __restrict__ beta,
    const float* __restrict__ vlw, const float* __restrict__ vlb,
    const float* __restrict__ vls, const float* __restrict__ vlo,
    u16* __restrict__ Zs)
{
  __shared__ u16 lds[38968];   // 77936 B -> 2 blocks/CU
  u16* XT = lds;               // [64][408]
  u16* VT = lds + 26112;       // [128][72], cols>=49 stay zero
  u16* Ph = lds + 35328;       // [65][56]
  int t = threadIdx.x, wv = t >> 6, l = t & 63, quad = l >> 4, l16 = l & 15;
  int b = blockIdx.x;
  const float* xb = x + (size_t)b * 18816;

  for (int e = t; e < 18816; e += 512) {
    int k = e / 49, n = e - k * 49;
    XT[n * 408 + k] = f2b(xb[e]);
  }
  for (int e = t; e < 3060; e += 512) {
    int r = e / 204, kk = e - r * 204;
    ((u32*)(XT + (49 + r) * 408))[kk] = 0;
  }
  for (int e = t; e < 4608; e += 512) ((u32*)VT)[e] = 0;
  __syncthreads();

  u16* Zb = Zs + (size_t)b * 50176;
  const u16* Pgb = Zb + POFF;
  for (int h = 0; h < 8; h++) {
    { // load this head's P tile (head-h Z writes never reach unread P: h*6272 <= POFF+h*2912)
      const u32* src = (const u32*)(Pgb + h * 2912);
      for (int e = t; e < 1456; e += 512) ((u32*)Ph)[e] = src[e];
    }
    f32x4 va[4] = {};
    const u16* Wr = Wv + (size_t)(h * 128 + wv * 16 + l16) * 384;
    #pragma unroll
    for (int ks = 0; ks < 12; ks++) {
      short8 af = *(const short8*)(Wr + ks * 32 + quad * 8);
      #pragma unroll
      for (int nt = 0; nt < 4; nt++) {
        short8 bf = *(const short8*)(&XT[(nt * 16 + l16) * 408 + ks * 32 + quad * 8]);
        va[nt] = __builtin_amdgcn_mfma_f32_16x16x32_bf16(af, bf, va[nt], 0, 0, 0);
      }
    }
    #pragma unroll
    for (int reg = 0; reg < 4; reg++) {
      int dl = wv * 16 + quad * 4 + reg;
      int c = h * 128 + dl;
      float al = alpha[512 + c], be = beta[512 + c];
      #pragma unroll
      for (int nt = 0; nt < 4; nt++) {
        int m = nt * 16 + l16;
        if (m < 49) VT[dl * 72 + m] = f2b(va[nt][reg] * al + be);
      }
    }
    __syncthreads();
    f32x4 oa[4] = {};
    #pragma unroll
    for (int ks2 = 0; ks2 < 2; ks2++) {
      int mb = ks2 * 32 + quad * 8;
      short8 bf = *(const short8*)(&VT[(wv * 16 + l16) * 72 + mb]);
      #pragma unroll
      for (int tn = 0; tn < 4; tn++) {
        short8 af = *(const short8*)(&Ph[(tn * 16 + l16) * 56 + mb]);
        oa[tn] = __builtin_amdgcn_mfma_f32_16x16x32_bf16(af, bf, oa[tn], 0, 0, 0);
      }
    }
    int d = wv * 16 + l16, c = h * 128 + d;
    float w9[9];
    #pragma unroll
    for (int j = 0; j < 9; j++) w9[j] = vlw[c * 9 + j];
    float sv = vls[c];
    float cb = sv * vlb[c] + vlo[c];
    const u16* vtr = &VT[d * 72];
    #pragma unroll
    for (int tn = 0; tn < 4; tn++) {
      #pragma unroll
      for (int r = 0; r < 4; r++) {
        int n = tn * 16 + quad * 4 + r;
        if (n < 49) {
          int yi = n / 7, xi = n - yi * 7;
          float conv = 0.f;
          #pragma unroll
          for (int ky = 0; ky < 3; ky++) {
            int y2 = yi + ky - 1;
            if (y2 < 0 || y2 > 6) continue;
            #pragma unroll
            for (int kx = 0; kx < 3; kx++) {
              int x2 = xi + kx - 1;
              if (x2 < 0 || x2 > 6) continue;
              conv += b2f(vtr[y2 * 7 + x2]) * w9[ky * 3 + kx];
            }
          }
          float z = oa[tn][r] + conv * sv + cb;
          float g = z * 0.5f * (1.0f + erff(z * 0.70710678118654752f));
          Zb[(size_t)c * 49 + n] = f2b(g);
        }
      }
    }
    __syncthreads();
  }
}

// ---- K4: output projection, 128x128 tiles, 2 batches/block, A from L2 ----
__global__ __launch_bounds__(512, 4) void k_proj(
    const u16* __restrict__ Wp, const u16* __restrict__ Zs,
    const float* __restrict__ alphap, const float* __restrict__ betap,
    float* __restrict__ out)
{
  __shared__ u16 Bs[128 * 152];   // 38912 B -> 4 blocks/CU
  int t = threadIdx.x, wv = t >> 6, l = t & 63, quad = l >> 4, l16 = l & 15;
  int mb = blockIdx.x % 3;
  size_t b0 = (size_t)(blockIdx.x / 3) * 2;
  f32x4 acc[8] = {};
  const u16* Wr = Wp + (size_t)(mb * 128 + wv * 16 + l16) * 1024;
  for (int k0 = 0; k0 < 1024; k0 += 128) {
    for (int e = t; e < 16384; e += 512) {
      int np = e & 127, kk = e >> 7;
      int pb = np >> 6, n = np & 63;
      u16 v = 0;
      if (n < 49) v = Zs[(b0 + pb) * 50176 + (size_t)(k0 + kk) * 49 + n];
      Bs[np * 152 + kk] = v;
    }
    __syncthreads();
    #pragma unroll
    for (int ksi = 0; ksi < 4; ksi++) {
      short8 af = *(const short8*)(Wr + k0 + ksi * 32 + quad * 8);
      #pragma unroll
      for (int nt = 0; nt < 8; nt++) {
        short8 bf = *(const short8*)(&Bs[(nt * 16 + l16) * 152 + ksi * 32 + quad * 8]);
        acc[nt] = __builtin_amdgcn_mfma_f32_16x16x32_bf16(af, bf, acc[nt], 0, 0, 0);
      }
    }
    __syncthreads();
  }
  #pragma unroll
  for (int reg = 0; reg < 4; reg++) {
    int c = mb * 128 + wv * 16 + quad * 4 + reg;
    float al = alphap[c], be = betap[c];
    #pragma unroll
    for (int nt = 0; nt < 8; nt++) {
      int np = nt * 16 + l16, pb = np >> 6, n = np & 63;
      if (n < 49) out[(b0 + pb) * 18816 + (size_t)c * 49 + n] = acc[nt][reg] * al + be;
    }
  }
}

extern "C" void kernel_launch(void* const* d_in, const int* in_sizes, int n_in,
                              void* d_out, int out_size, void* d_ws, size_t ws_size,
                              hipStream_t stream) {
  const float* x    = (const float*)d_in[0];
  const float* qw   = (const float*)d_in[1];
  const float* qb   = (const float*)d_in[2];
  const float* qs   = (const float*)d_in[3];
  const float* qo   = (const float*)d_in[4];
  const float* kw   = (const float*)d_in[5];
  const float* kb   = (const float*)d_in[6];
  const float* ks   = (const float*)d_in[7];
  const float* ko   = (const float*)d_in[8];
  const float* vw   = (const float*)d_in[9];
  const float* vb   = (const float*)d_in[10];
  const float* vs   = (const float*)d_in[11];
  const float* vo   = (const float*)d_in[12];
  const float* vlw  = (const float*)d_in[13];
  const float* vlb  = (const float*)d_in[14];
  const float* vls  = (const float*)d_in[15];
  const float* vlo  = (const float*)d_in[16];
  const float* th1w = (const float*)d_in[17];
  const float* th1b = (const float*)d_in[18];
  const float* th2w = (const float*)d_in[19];
  const float* th2b = (const float*)d_in[20];
  const float* pw   = (const float*)d_in[21];
  const float* pb   = (const float*)d_in[22];
  const float* ps   = (const float*)d_in[23];
  const float* po   = (const float*)d_in[24];
  const float* ab   = (const float*)d_in[25];
  float* out = (float*)d_out;
  char* ws = (char*)d_ws;

  // ws layout — total ~104.8 MB (proven safe in round 5)
  float* bias2  = (float*)(ws + 0);          // 19208 f
  float* alpha  = (float*)(ws + 77056);      // 1536 f
  float* beta   = (float*)(ws + 83200);      // 1536 f
  float* alphap = (float*)(ws + 89344);      // 384 f
  float* betap  = (float*)(ws + 90880);      // 384 f
  u16*   Wqk16  = (u16*)(ws + 92416);        // [512][384]
  u16*   Wv16   = (u16*)(ws + 485632);       // [1024][384]
  u16*   Wp16   = (u16*)(ws + 1272064);      // [384][1024]
  u16*   Zs     = (u16*)(ws + 2058496);      // 1024 slabs of 50176 u16 (Z + P-in-tail)

  k_pre<<<3923, 256, 0, stream>>>(th1w, th1b, ab, qb, qs, qo, kb, ks, ko,
                                  vb, vs, vo, pb, ps, po, qw, kw, vw, pw,
                                  bias2, alpha, beta, alphap, betap,
                                  Wqk16, Wv16, Wp16);
  k_qk<<<1024, 512, 0, stream>>>(x, Wqk16, alpha, beta, Zs);
  k_mix<<<1024, 256, 0, stream>>>(Zs, bias2, th1w, th1b, th2w, th2b);
  k_av<<<1024, 512, 0, stream>>>(x, Wv16, alpha, beta, vlw, vlb, vls, vlo, Zs);
  k_proj<<<1536, 512, 0, stream>>>(Wp16, Zs, alphap, betap, out);
}